// Round 6
// baseline (197.346 us; speedup 1.0000x reference)
//
#include <hip/hip_runtime.h>

// BIATT: B=16, Lc=Lp=1024, D=128, H=4, PFEAT=1024. All inputs fp32.
// Algebra: cv is rank-1 (c[b,l]*cp[d]) => A = tanh(c[b,l]*g[b,h,m]);
// scores reduce to 1D sums over tanh of an outer product.
// Precision: split-bf16 (hi+lo) MFMA => ~fp32-equivalent GEMMs.
// K2: zero-LDS, XCD-local (bid = q*256 + mtile keeps pv tile on one XCD's L2).

using bf16x8 = __attribute__((ext_vector_type(8))) short;
using u16x8  = __attribute__((ext_vector_type(8))) unsigned short;
using f32x4  = __attribute__((ext_vector_type(4))) float;

#define TWO_LOG2E 2.8853900817779268f

__device__ __forceinline__ float exp2_raw(float x){
#if __has_builtin(__builtin_amdgcn_exp2f)
  return __builtin_amdgcn_exp2f(x);
#else
  float r; asm("v_exp_f32 %0, %1" : "=v"(r) : "v"(x)); return r;
#endif
}
__device__ __forceinline__ float tanh_fast(float x){
  float e = exp2_raw(x * TWO_LOG2E);
  return fmaf(-2.0f, __builtin_amdgcn_rcpf(e + 1.0f), 1.0f);
}
__device__ __forceinline__ unsigned short f2bf(float f){
  unsigned u = __float_as_uint(f);
  u = (u + 0x7FFFu + ((u >> 16) & 1u)) >> 16; // RNE
  return (unsigned short)u;
}
__device__ __forceinline__ float bf2f(unsigned short s){
  return __uint_as_float((unsigned)s << 16);
}
__device__ __forceinline__ unsigned cvt_pk_bf16(float a, float b){
  unsigned r;
  asm("v_cvt_pk_bf16_f32 %0, %1, %2" : "=v"(r) : "v"(a), "v"(b));
  return r;
}
// split 8 f32 -> hi/lo bf16x8 fragments (lo = x - hi is exact in f32)
__device__ __forceinline__ void split8(const float4& x, const float4& y, bf16x8& hi, bf16x8& lo){
  unsigned h0 = cvt_pk_bf16(x.x, x.y);
  unsigned h1 = cvt_pk_bf16(x.z, x.w);
  unsigned h2 = cvt_pk_bf16(y.x, y.y);
  unsigned h3 = cvt_pk_bf16(y.z, y.w);
  float r0 = x.x - __uint_as_float(h0 << 16);
  float r1 = x.y - __uint_as_float(h0 & 0xffff0000u);
  float r2 = x.z - __uint_as_float(h1 << 16);
  float r3 = x.w - __uint_as_float(h1 & 0xffff0000u);
  float r4 = y.x - __uint_as_float(h2 << 16);
  float r5 = y.y - __uint_as_float(h2 & 0xffff0000u);
  float r6 = y.z - __uint_as_float(h3 << 16);
  float r7 = y.w - __uint_as_float(h3 & 0xffff0000u);
  uint4 H = make_uint4(h0, h1, h2, h3);
  uint4 L = make_uint4(cvt_pk_bf16(r0, r1), cvt_pk_bf16(r2, r3),
                       cvt_pk_bf16(r4, r5), cvt_pk_bf16(r6, r7));
  hi = __builtin_bit_cast(bf16x8, H);
  lo = __builtin_bit_cast(bf16x8, L);
}

// ---------------------------------------------------------------- K0a: small precomputes + c-side tanh maps
__global__ __launch_bounds__(256) void k0a_prep(
    const float* __restrict__ c, const float* __restrict__ c_mask,
    const float* __restrict__ c_param,
    const float* __restrict__ U, const float* __restrict__ W_c2p,
    const float* __restrict__ Wh_c, const float* __restrict__ bh_c,
    const float* __restrict__ b_c2p, const float* __restrict__ Wa_c,
    const float* __restrict__ Wa_p, const float* __restrict__ W_comb_c,
    const float* __restrict__ ba_c,
    float* __restrict__ uh, float* __restrict__ wccv,
    float* __restrict__ score_c, float2* __restrict__ pairP)
{
  int bid = blockIdx.x, t = threadIdx.x;
  if (bid < 4) {
    int h = bid;
    if (t < 128) {
      float s_uh = 0.f, s_wcc = 0.f;
      for (int d = 0; d < 128; ++d) {
        float cp = c_param[d];
        s_uh  += cp * U[(h*128 + d)*128 + t];
        s_wcc += cp * W_comb_c[(h*128 + d)*128 + t];
      }
      uh[h*128 + t]   = s_uh;
      wccv[h*128 + t] = s_wcc;
    }
  } else {
    int i = bid - 4;
    int b = i >> 4, h = (i >> 2) & 3, lc = i & 3;
    __shared__ float whc_l[128], wc2p_l[128], bhc_l[128], bc2p_l[128], wac1_l[128], wap2_l[128];
    if (t < 128) {
      float s1 = 0.f, s2 = 0.f;
      for (int d = 0; d < 128; ++d) {
        float cp = c_param[d];
        s1 += cp * Wh_c[(h*128 + d)*128 + t];
        s2 += cp * W_c2p[(h*128 + d)*128 + t];
      }
      whc_l[t] = s1; wc2p_l[t] = s2;
      bhc_l[t]  = bh_c[h*128 + t];
      bc2p_l[t] = b_c2p[h*128 + t];
      wac1_l[t] = Wa_c[h*256 + t];
      wap2_l[t] = Wa_p[h*256 + 128 + t];
    }
    __syncthreads();
    int l = lc*256 + t;
    float cl = c[b*1024 + l];
    float a1 = 0.f, a2 = 0.f;
    for (int e = 0; e < 128; ++e) {
      a1 += wac1_l[e] * tanh_fast(cl*whc_l[e]  + bhc_l[e]);
      a2 += wap2_l[e] * tanh_fast(cl*wc2p_l[e] + bc2p_l[e]);
    }
    int o = (b*4 + h)*1024 + l;
    score_c[o] = a1 + ba_c[h];                     // base: hcw + ba_c
    pairP[o] = make_float2(TWO_LOG2E * cl, c_mask[b*1024 + l] * a2); // (kappa, ctw)
  }
}

// ---------------------------------------------------------------- K0t: coalesced LDS-tile transposes -> hi/lo bf16
// 64 blocks: 0..31 p_param (1024x128), 32..47 W_p2c, 48..63 Wh_p (per-head 128x128).
__global__ __launch_bounds__(256) void k0t_transpose(
    const float* __restrict__ p_param, const float* __restrict__ W_p2c,
    const float* __restrict__ Wh_p,
    unsigned short* __restrict__ ppT_hi, unsigned short* __restrict__ ppT_lo,
    unsigned short* __restrict__ wp2cT_hi, unsigned short* __restrict__ wp2cT_lo,
    unsigned short* __restrict__ whpT_hi, unsigned short* __restrict__ whpT_lo)
{
  __shared__ float T[64*68];
  int bid = blockIdx.x, t = threadIdx.x;
  const float* src; unsigned short* dh; unsigned short* dl;
  int k0, e0, dpitch, drow0;
  if (bid < 32) {                 // pp tile: k-tile = bid>>1 (64 rows), e-tile = bid&1
    k0 = (bid >> 1)*64; e0 = (bid & 1)*64;
    src = p_param; dh = ppT_hi; dl = ppT_lo; dpitch = 1024; drow0 = e0;
  } else if (bid < 48) {
    int w = bid - 32; int h = w >> 2, ki = (w >> 1) & 1, ej = w & 1;
    k0 = ki*64; e0 = ej*64;
    src = W_p2c + h*16384; dh = wp2cT_hi; dl = wp2cT_lo; dpitch = 128;
    drow0 = h*128 + e0;
  } else {
    int w = bid - 48; int h = w >> 2, ki = (w >> 1) & 1, ej = w & 1;
    k0 = ki*64; e0 = ej*64;
    src = Wh_p + h*16384; dh = whpT_hi; dl = whpT_lo; dpitch = 128;
    drow0 = h*128 + e0;
  }
  { // coalesced read: row r = t>>2, col segment (t&3)*4 + j*16
    int r = t >> 2, cs = (t & 3)*4;
    const float* s = src + (k0 + r)*128 + e0 + cs;
    #pragma unroll
    for (int j = 0; j < 4; ++j) {
      float4 v = *(const float4*)(s + j*16);
      *(float4*)&T[r*68 + cs + j*16] = v;
    }
  }
  __syncthreads();
  { // transpose out: e-row = t>>2, k segment (t&3)*16
    int e = t >> 2, ks = (t & 3)*16;
    unsigned short hs[16], ls[16];
    #pragma unroll
    for (int j = 0; j < 16; ++j) {
      float v = T[(ks + j)*68 + e];
      unsigned short hh = f2bf(v);
      hs[j] = hh; ls[j] = f2bf(v - bf2f(hh));
    }
    unsigned short* ph = dh + (drow0 + e)*dpitch + k0 + ks;
    unsigned short* pl = dl + (drow0 + e)*dpitch + k0 + ks;
    *(u16x8*)ph       = *(u16x8*)&hs[0];
    *(u16x8*)(ph + 8) = *(u16x8*)&hs[8];
    *(u16x8*)pl       = *(u16x8*)&ls[0];
    *(u16x8*)(pl + 8) = *(u16x8*)&ls[8];
  }
}

// ---------------------------------------------------------------- K1: pv = p @ p_param (split-bf16 MFMA) + g epilogue
__global__ __launch_bounds__(256) void k1_pv(
    const float* __restrict__ p,
    const unsigned short* __restrict__ ppT_hi, const unsigned short* __restrict__ ppT_lo,
    const float* __restrict__ uh,
    float* __restrict__ pv_f32, float* __restrict__ g_arr)
{
  __shared__ __align__(16) short Bh[128*72];
  __shared__ __align__(16) short Bl[128*72];
  int t = threadIdx.x;
  int row0 = blockIdx.x * 64;
  int w = t >> 6, lane = t & 63;
  int l15 = lane & 15, l4 = lane >> 4;

  int bcol = t >> 1, bkh = (t & 1) * 32;
  const unsigned short* gBh = ppT_hi + bcol*1024 + bkh;
  const unsigned short* gBl = ppT_lo + bcol*1024 + bkh;
  short* sBh = &Bh[bcol*72 + bkh];
  short* sBl = &Bl[bcol*72 + bkh];

  const float* gA = p + (row0 + w*16 + l15)*1024 + l4*8;

  u16x8 rb[8];        // hi[0..3], lo[4..7]
  float4 ra[4];       // (ks,half): [2*ks+half]

  #pragma unroll
  for (int j = 0; j < 4; ++j) {
    rb[j]   = *(const u16x8*)(gBh + j*8);
    rb[4+j] = *(const u16x8*)(gBl + j*8);
  }
  #pragma unroll
  for (int j = 0; j < 4; ++j)
    ra[j] = *(const float4*)(gA + (j>>1)*32 + (j&1)*4);

  f32x4 acc[8];
  #pragma unroll
  for (int n = 0; n < 8; ++n) acc[n] = (f32x4){0.f,0.f,0.f,0.f};

  for (int kc = 0; kc < 16; ++kc) {
    __syncthreads();
    #pragma unroll
    for (int j = 0; j < 4; ++j) {
      *(u16x8*)(sBh + j*8) = rb[j];
      *(u16x8*)(sBl + j*8) = rb[4+j];
    }
    if (kc < 15) {
      #pragma unroll
      for (int j = 0; j < 4; ++j) {
        rb[j]   = *(const u16x8*)(gBh + (kc+1)*64 + j*8);
        rb[4+j] = *(const u16x8*)(gBl + (kc+1)*64 + j*8);
      }
    }
    float4 ran0, ran1, ran2, ran3;
    if (kc < 15) {
      const float* gAn = gA + (kc+1)*64;
      ran0 = *(const float4*)(gAn);
      ran1 = *(const float4*)(gAn + 4);
      ran2 = *(const float4*)(gAn + 32);
      ran3 = *(const float4*)(gAn + 36);
    }
    __syncthreads();
    #pragma unroll
    for (int ks = 0; ks < 2; ++ks) {
      bf16x8 ah, al;
      split8(ra[2*ks], ra[2*ks+1], ah, al);
      #pragma unroll
      for (int ct = 0; ct < 8; ++ct) {
        bf16x8 bh = *(const bf16x8*)&Bh[(ct*16 + l15)*72 + ks*32 + l4*8];
        bf16x8 bl = *(const bf16x8*)&Bl[(ct*16 + l15)*72 + ks*32 + l4*8];
        acc[ct] = __builtin_amdgcn_mfma_f32_16x16x32_bf16(ah, bh, acc[ct], 0, 0, 0);
        acc[ct] = __builtin_amdgcn_mfma_f32_16x16x32_bf16(ah, bl, acc[ct], 0, 0, 0);
        acc[ct] = __builtin_amdgcn_mfma_f32_16x16x32_bf16(al, bh, acc[ct], 0, 0, 0);
      }
    }
    if (kc < 15) { ra[0] = ran0; ra[1] = ran1; ra[2] = ran2; ra[3] = ran3; }
  }

  #pragma unroll
  for (int ct = 0; ct < 8; ++ct) {
    int col = ct*16 + l15;
    #pragma unroll
    for (int r = 0; r < 4; ++r) {
      int row = row0 + w*16 + l4*4 + r;
      pv_f32[row*128 + col] = acc[ct][r];
    }
  }

  // g epilogue: g[bh,m] = sum_d pv[m,d]*uh[h,d] from regs
  #pragma unroll
  for (int h = 0; h < 4; ++h) {
    float s0 = 0.f, s1 = 0.f, s2 = 0.f, s3 = 0.f;
    #pragma unroll
    for (int ct = 0; ct < 8; ++ct) {
      float u = uh[h*128 + ct*16 + l15];
      s0 = fmaf(acc[ct][0], u, s0);
      s1 = fmaf(acc[ct][1], u, s1);
      s2 = fmaf(acc[ct][2], u, s2);
      s3 = fmaf(acc[ct][3], u, s3);
    }
    #pragma unroll
    for (int off = 1; off < 16; off <<= 1) {
      s0 += __shfl_xor(s0, off, 64);
      s1 += __shfl_xor(s1, off, 64);
      s2 += __shfl_xor(s2, off, 64);
      s3 += __shfl_xor(s3, off, 64);
    }
    if (l15 == 0) {
      int row = row0 + w*16 + l4*4;
      int bb = row >> 10, m = row & 1023;
      float4 gv = make_float4(s0, s1, s2, s3);
      *(float4*)&g_arr[(bb*4 + h)*1024 + m] = gv;
    }
  }
}

// ---------------------------------------------------------------- K2: flat per-head tanh-path partials (no LDS, no barriers)
// grid 1024 = q(4) x mtile(256; 64 rows). bid = q*256 + mtile -> all q of one
// mtile share an XCD (256 % 8 == 0) -> pv tile stays in that XCD's L2.
__global__ __launch_bounds__(256) void k2_head(
    const float* __restrict__ pv_f32,
    const unsigned short* __restrict__ wp2cT_hi, const unsigned short* __restrict__ wp2cT_lo,
    const unsigned short* __restrict__ whpT_hi, const unsigned short* __restrict__ whpT_lo,
    const float* __restrict__ b_p2c, const float* __restrict__ bh_p,
    const float* __restrict__ Wa_c, const float* __restrict__ Wa_p,
    float* __restrict__ part_c, float* __restrict__ part_p)
{
  int t = threadIdx.x;
  int bid = blockIdx.x;
  int q = bid >> 8;
  int mtile = bid & 255;
  int w = t >> 6, lane = t & 63;
  int l15 = lane & 15, l4 = lane >> 4;
  int rowbase = mtile*64 + w*16;
  int b = mtile >> 4;

  // A fragments (16 rows/wave, read once, split hi/lo in-reg)
  bf16x8 ah[4], al[4];
  {
    const float* ga = pv_f32 + (rowbase + l15)*128 + l4*8;
    #pragma unroll
    for (int kt = 0; kt < 4; ++kt) {
      float4 x = *(const float4*)(ga + kt*32);
      float4 y = *(const float4*)(ga + kt*32 + 4);
      split8(x, y, ah[kt], al[kt]);
    }
  }

  int col0 = q*32 + l15, col1 = col0 + 16;
  int m0 = (rowbase + l4*4) & 1023;

  #pragma unroll
  for (int path = 0; path < 2; ++path) {
    const unsigned short* Bh_g = path ? whpT_hi : wp2cT_hi;
    const unsigned short* Bl_g = path ? whpT_lo : wp2cT_lo;
    const float* bias_g = path ? bh_p : b_p2c;
    float* outp = path ? part_p : part_c;

    for (int h = 0; h < 4; ++h) {
      bf16x8 bhf[2][4], blf[2][4];
      #pragma unroll
      for (int n = 0; n < 2; ++n) {
        const unsigned short* gb = Bh_g + (h*128 + q*32 + n*16 + l15)*128 + l4*8;
        const unsigned short* gl = Bl_g + (h*128 + q*32 + n*16 + l15)*128 + l4*8;
        #pragma unroll
        for (int kt = 0; kt < 4; ++kt) {
          bhf[n][kt] = *(const bf16x8*)(gb + kt*32);
          blf[n][kt] = *(const bf16x8*)(gl + kt*32);
        }
      }
      float bias0 = bias_g[h*128 + col0], bias1 = bias_g[h*128 + col1];
      float wa0, wa1;
      if (path) { wa0 = Wa_p[h*256 + col0];       wa1 = Wa_p[h*256 + col1]; }
      else      { wa0 = Wa_c[h*256 + 128 + col0]; wa1 = Wa_c[h*256 + 128 + col1]; }

      f32x4 acc0 = (f32x4){0.f,0.f,0.f,0.f};
      f32x4 acc1 = (f32x4){0.f,0.f,0.f,0.f};
      #pragma unroll
      for (int kt = 0; kt < 4; ++kt) {
        acc0 = __builtin_amdgcn_mfma_f32_16x16x32_bf16(ah[kt], bhf[0][kt], acc0, 0, 0, 0);
        acc1 = __builtin_amdgcn_mfma_f32_16x16x32_bf16(ah[kt], bhf[1][kt], acc1, 0, 0, 0);
        acc0 = __builtin_amdgcn_mfma_f32_16x16x32_bf16(ah[kt], blf[0][kt], acc0, 0, 0, 0);
        acc1 = __builtin_amdgcn_mfma_f32_16x16x32_bf16(ah[kt], blf[1][kt], acc1, 0, 0, 0);
        acc0 = __builtin_amdgcn_mfma_f32_16x16x32_bf16(al[kt], bhf[0][kt], acc0, 0, 0, 0);
        acc1 = __builtin_amdgcn_mfma_f32_16x16x32_bf16(al[kt], bhf[1][kt], acc1, 0, 0, 0);
      }
      float pp0 = wa0*tanh_fast(acc0[0] + bias0) + wa1*tanh_fast(acc1[0] + bias1);
      float pp1 = wa0*tanh_fast(acc0[1] + bias0) + wa1*tanh_fast(acc1[1] + bias1);
      float pp2 = wa0*tanh_fast(acc0[2] + bias0) + wa1*tanh_fast(acc1[2] + bias1);
      float pp3 = wa0*tanh_fast(acc0[3] + bias0) + wa1*tanh_fast(acc1[3] + bias1);
      #pragma unroll
      for (int off = 1; off < 16; off <<= 1) {
        pp0 += __shfl_xor(pp0, off, 64);
        pp1 += __shfl_xor(pp1, off, 64);
        pp2 += __shfl_xor(pp2, off, 64);
        pp3 += __shfl_xor(pp3, off, 64);
      }
      if (l15 == 0) {
        *(float4*)&outp[q*65536 + (b*4 + h)*1024 + m0] = make_float4(pp0, pp1, pp2, pp3);
      }
    }
  }
}

// ---------------------------------------------------------------- K3: combine partials -> pairC, score_p
__global__ __launch_bounds__(256) void k3_pack(
    const float* __restrict__ g_arr, const float* __restrict__ part_c,
    const float* __restrict__ part_p, const float* __restrict__ p_mask,
    const float* __restrict__ ba_p,
    float2* __restrict__ pairC, float* __restrict__ score_p)
{
  int i0 = (blockIdx.x*256 + threadIdx.x)*4;
  int bh = i0 >> 10, h = bh & 3, b = bh >> 2, m = i0 & 1023;
  float4 g4 = *(const float4*)&g_arr[i0];
  float4 c0 = *(const float4*)&part_c[i0];
  float4 c1 = *(const float4*)&part_c[65536 + i0];
  float4 c2 = *(const float4*)&part_c[131072 + i0];
  float4 c3 = *(const float4*)&part_c[196608 + i0];
  float4 p0 = *(const float4*)&part_p[i0];
  float4 p1 = *(const float4*)&part_p[65536 + i0];
  float4 p2 = *(const float4*)&part_p[131072 + i0];
  float4 p3 = *(const float4*)&part_p[196608 + i0];
  float4 mk = *(const float4*)&p_mask[b*1024 + m];
  float bap = ba_p[h];
  pairC[i0+0] = make_float2(TWO_LOG2E*g4.x, mk.x*(c0.x+c1.x+c2.x+c3.x));
  pairC[i0+1] = make_float2(TWO_LOG2E*g4.y, mk.y*(c0.y+c1.y+c2.y+c3.y));
  pairC[i0+2] = make_float2(TWO_LOG2E*g4.z, mk.z*(c0.z+c1.z+c2.z+c3.z));
  pairC[i0+3] = make_float2(TWO_LOG2E*g4.w, mk.w*(c0.w+c1.w+c2.w+c3.w));
  float4 sp = make_float4(bap + p0.x+p1.x+p2.x+p3.x, bap + p0.y+p1.y+p2.y+p3.y,
                          bap + p0.z+p1.z+p2.z+p3.z, bap + p0.w+p1.w+p2.w+p3.w);
  *(float4*)&score_p[i0] = sp;
}

// ---------------------------------------------------------------- K4: tanh outer-product reductions
// grid 2048 = side(2) x b(16) x h(4) x alpha-chunk(4) x j-chunk(4); 256 thr.
__global__ __launch_bounds__(256) void k4_scores(
    const float* __restrict__ c, const float* __restrict__ c_mask, const float* __restrict__ p_mask,
    const float* __restrict__ g_arr,
    const float2* __restrict__ pairC, const float2* __restrict__ pairP,
    float* __restrict__ score_c, float* __restrict__ score_p)
{
  __shared__ float red[4];
  int bid = blockIdx.x, t = threadIdx.x;
  int side = bid >> 10;
  int r = bid & 1023;
  int b = r >> 6, h = (r >> 4) & 3, ac = (r >> 2) & 3, jc = r & 3;
  int bh = b*4 + h;
  const float2* pair = (side ? pairP : pairC) + bh*1024 + jc*256;
  int ai = ac*256 + t;
  float alpha = side ? g_arr[bh*1024 + ai] : c[b*1024 + ai];
  float mask  = side ? p_mask[b*1024 + ai] : c_mask[b*1024 + ai];

  float partB = pair[t].y;
  #pragma unroll
  for (int off = 1; off < 64; off <<= 1) partB += __shfl_xor(partB, off, 64);
  if ((t & 63) == 0) red[t >> 6] = partB;
  __syncthreads();
  float sB = red[0] + red[1] + red[2] + red[3];

  float acc = 0.f;
  #pragma unroll 16
  for (int j = 0; j < 256; ++j) {
    float2 gb = pair[j];                      // block-uniform -> scalar loads
    float e = exp2_raw(alpha * gb.x);         // e^{2*alpha*g}, raw v_exp_f32
    acc = fmaf(gb.y, __builtin_amdgcn_rcpf(e + 1.0f), acc);
  }
  float part = mask * (sB - 2.0f*acc);
  atomicAdd((side ? score_p : score_c) + bh*1024 + ai, part);
}

// ---------------------------------------------------------------- K5: masked softmax + pools
__device__ __forceinline__ float blk_red_max(float v, float* red, int t){
  red[t] = v; __syncthreads();
  for (int s = 128; s; s >>= 1) { if (t < s) red[t] = fmaxf(red[t], red[t+s]); __syncthreads(); }
  float r = red[0]; __syncthreads();
  return r;
}
__device__ __forceinline__ float blk_red_sum(float v, float* red, int t){
  red[t] = v; __syncthreads();
  for (int s = 128; s; s >>= 1) { if (t < s) red[t] += red[t+s]; __syncthreads(); }
  float r = red[0]; __syncthreads();
  return r;
}

__global__ __launch_bounds__(256) void k5_soft(
    const float* __restrict__ c, const float* __restrict__ c_mask, const float* __restrict__ p_mask,
    const float* __restrict__ score_c, const float* __restrict__ score_p,
    const float* __restrict__ pv_f32,
    float* __restrict__ s_c, float* __restrict__ pf_pool)
{
  __shared__ float sv[1024];
  __shared__ float red[256];
  int bid = blockIdx.x, t = threadIdx.x;
  bool sideP = bid >= 64;
  int i = bid & 63;
  int b = i >> 2, h = i & 3, bh = b*4 + h;
  const float* sc = (sideP ? score_p : score_c) + bh*1024;
  const float* mk = (sideP ? p_mask : c_mask) + b*1024;

  float v[4];
  float mx = -1e30f;
  #pragma unroll
  for (int j = 0; j < 4; ++j) { v[j] = sc[t + j*256]; mx = fmaxf(mx, v[j]); }
  mx = blk_red_max(mx, red, t);
  float sum = 0.f;
  #pragma unroll
  for (int j = 0; j < 4; ++j) {
    float e = exp2_raw((v[j] - mx) * 1.4426950408889634f) * mk[t + j*256];
    sv[t + j*256] = e;
    sum += e;
  }
  sum = blk_red_sum(sum, red, t);
  float rinv = __fdividef(1.0f, sum + 1e-6f);

  if (!sideP) {
    float a = 0.f;
    #pragma unroll
    for (int j = 0; j < 4; ++j) a += sv[t + j*256] * rinv * c[b*1024 + t + j*256];
    a = blk_red_sum(a, red, t);
    if (t == 0) s_c[bh] = a;
  } else {
    #pragma unroll
    for (int j = 0; j < 4; ++j) sv[t + j*256] *= rinv;
    __syncthreads();
    int e = t & 127, half = t >> 7;
    float acc = 0.f;
    const float* base = pv_f32 + (b*1024 + half*512)*128 + e;
    #pragma unroll 4
    for (int m = 0; m < 512; ++m) acc += sv[half*512 + m] * base[m*128];
    red[t] = acc; __syncthreads();
    if (t < 128) pf_pool[bh*128 + t] = red[t] + red[t + 128];
  }
}

// ---------------------------------------------------------------- K6: finals + outer product
__global__ __launch_bounds__(256) void k6_final(
    const float* __restrict__ s_c, const float* __restrict__ wccv,
    const float* __restrict__ b_comb_c, const float* __restrict__ pf_pool,
    const float* __restrict__ W_comb_p, const float* __restrict__ b_comb_p,
    float* __restrict__ out)
{
  __shared__ float pfr[512];
  __shared__ float cfl[128], pfl[128];
  int b = blockIdx.x, t = threadIdx.x;
  pfr[t]       = pf_pool[b*512 + t];
  pfr[t + 256] = pf_pool[b*512 + t + 256];
  __syncthreads();
  if (t < 128) {
    float cf = b_comb_c[t];
    #pragma unroll
    for (int h = 0; h < 4; ++h) cf += s_c[b*4 + h] * wccv[h*128 + t];
    float pf = b_comb_p[t];
    #pragma unroll 8
    for (int i = 0; i < 512; ++i) pf += pfr[i] * W_comb_p[i*128 + t];
    cfl[t] = cf; pfl[t] = pf;
  }
  __syncthreads();
  #pragma unroll
  for (int k = 0; k < 64; ++k) {
    int idx = k*256 + t;
    out[b*16384 + idx] = cfl[idx >> 7] * pfl[idx & 127];
  }
}

// ---------------------------------------------------------------- launcher
extern "C" void kernel_launch(void* const* d_in, const int* in_sizes, int n_in,
                              void* d_out, int out_size, void* d_ws, size_t ws_size,
                              hipStream_t stream)
{
  const float* c        = (const float*)d_in[0];
  const float* c_mask   = (const float*)d_in[1];
  const float* p        = (const float*)d_in[2];
  const float* p_mask   = (const float*)d_in[3];
  const float* c_param  = (const float*)d_in[4];
  const float* p_param  = (const float*)d_in[5];
  const float* U        = (const float*)d_in[6];
  const float* W_p2c    = (const float*)d_in[7];
  const float* b_p2c    = (const float*)d_in[8];
  const float* W_c2p    = (const float*)d_in[9];
  const float* b_c2p    = (const float*)d_in[10];
  const float* Wh_c     = (const float*)d_in[11];
  const float* bh_c     = (const float*)d_in[12];
  const float* Wh_p     = (const float*)d_in[13];
  const float* bh_p     = (const float*)d_in[14];
  const float* Wa_c     = (const float*)d_in[15];
  const float* ba_c     = (const float*)d_in[16];
  const float* Wa_p     = (const float*)d_in[17];
  const float* ba_p     = (const float*)d_in[18];
  const float* W_comb_c = (const float*)d_in[19];
  const float* b_comb_c = (const float*)d_in[20];
  const float* W_comb_p = (const float*)d_in[21];
  const float* b_comb_p = (const float*)d_in[22];
  float* out = (float*)d_out;

  char* ws = (char*)d_ws;
  float*          pv_f32   = (float*)         (ws + 0);
  unsigned short* ppT_hi   = (unsigned short*)(ws + 8388608);
  unsigned short* ppT_lo   = (unsigned short*)(ws + 8650752);
  unsigned short* wp2cT_hi = (unsigned short*)(ws + 8912896);
  unsigned short* wp2cT_lo = (unsigned short*)(ws + 9043968);
  unsigned short* whpT_hi  = (unsigned short*)(ws + 9175040);
  unsigned short* whpT_lo  = (unsigned short*)(ws + 9306112);
  float*          uh       = (float*)         (ws + 9437184);
  float*          wccv     = (float*)         (ws + 9439232);
  float*          g_arr    = (float*)         (ws + 9441280);
  float2*         pairC    = (float2*)        (ws + 9703424);
  float2*         pairP    = (float2*)        (ws + 10227712);
  float*          score_c  = (float*)         (ws + 10752000);
  float*          score_p  = (float*)         (ws + 11014144);
  float*          s_c      = (float*)         (ws + 11276288);
  float*          pf_pool  = (float*)         (ws + 11276544);
  float*          part_c   = (float*)         (ws + 11284736);
  float*          part_p   = (float*)         (ws + 12333312);

  k0a_prep<<<dim3(260), dim3(256), 0, stream>>>(
      c, c_mask, c_param, U, W_c2p, Wh_c, bh_c, b_c2p, Wa_c, Wa_p,
      W_comb_c, ba_c, uh, wccv, score_c, pairP);

  k0t_transpose<<<dim3(64), dim3(256), 0, stream>>>(
      p_param, W_p2c, Wh_p,
      ppT_hi, ppT_lo, wp2cT_hi, wp2cT_lo, whpT_hi, whpT_lo);

  k1_pv<<<dim3(256), dim3(256), 0, stream>>>(p, ppT_hi, ppT_lo, uh, pv_f32, g_arr);

  k2_head<<<dim3(1024), dim3(256), 0, stream>>>(
      pv_f32, wp2cT_hi, wp2cT_lo, whpT_hi, whpT_lo,
      b_p2c, bh_p, Wa_c, Wa_p, part_c, part_p);

  k3_pack<<<dim3(64), dim3(256), 0, stream>>>(
      g_arr, part_c, part_p, p_mask, ba_p, pairC, score_p);

  k4_scores<<<dim3(2048), dim3(256), 0, stream>>>(
      c, c_mask, p_mask, g_arr, pairC, pairP, score_c, score_p);

  k5_soft<<<dim3(128), dim3(256), 0, stream>>>(
      c, c_mask, p_mask, score_c, score_p, pv_f32, s_c, pf_pool);

  k6_final<<<dim3(16), dim3(256), 0, stream>>>(
      s_c, wccv, b_comb_c, pf_pool, W_comb_p, b_comb_p, out);
}

// Round 8
// 156.991 us; speedup vs baseline: 1.2571x; 1.2571x over previous
//
#include <hip/hip_runtime.h>

// BIATT: B=16, Lc=Lp=1024, D=128, H=4, PFEAT=1024. All inputs fp32.
// Algebra: cv is rank-1 (c[b,l]*cp[d]) => A = tanh(c[b,l]*g[b,h,m]);
// scores reduce to 1D sums over tanh of an outer product.
// K1 (K=1024) uses split-bf16 hi/lo MFMA (~fp32); K2 (K=128, score-level)
// uses single-bf16 (err ~2e-3 on scores, negligible vs 0.107 threshold).
// K2 is weight-stationary: one (path,h) per block, W staged once in LDS.
// R8 fix: K2 LDS staging was half-filled (4 u16x8/thread); now 8 (64 shorts).

using bf16x8 = __attribute__((ext_vector_type(8))) short;
using u16x8  = __attribute__((ext_vector_type(8))) unsigned short;
using f32x4  = __attribute__((ext_vector_type(4))) float;

#define TWO_LOG2E 2.8853900817779268f

__device__ __forceinline__ float exp2_raw(float x){
#if __has_builtin(__builtin_amdgcn_exp2f)
  return __builtin_amdgcn_exp2f(x);
#else
  float r; asm("v_exp_f32 %0, %1" : "=v"(r) : "v"(x)); return r;
#endif
}
__device__ __forceinline__ float tanh_fast(float x){
  float e = exp2_raw(x * TWO_LOG2E);
  return fmaf(-2.0f, __builtin_amdgcn_rcpf(e + 1.0f), 1.0f);
}
__device__ __forceinline__ unsigned short f2bf(float f){
  unsigned u = __float_as_uint(f);
  u = (u + 0x7FFFu + ((u >> 16) & 1u)) >> 16; // RNE
  return (unsigned short)u;
}
__device__ __forceinline__ float bf2f(unsigned short s){
  return __uint_as_float((unsigned)s << 16);
}
__device__ __forceinline__ unsigned cvt_pk_bf16(float a, float b){
  unsigned r;
  asm("v_cvt_pk_bf16_f32 %0, %1, %2" : "=v"(r) : "v"(a), "v"(b));
  return r;
}
// split 8 f32 -> hi/lo bf16x8 fragments (lo = x - hi is exact in f32)
__device__ __forceinline__ void split8(const float4& x, const float4& y, bf16x8& hi, bf16x8& lo){
  unsigned h0 = cvt_pk_bf16(x.x, x.y);
  unsigned h1 = cvt_pk_bf16(x.z, x.w);
  unsigned h2 = cvt_pk_bf16(y.x, y.y);
  unsigned h3 = cvt_pk_bf16(y.z, y.w);
  float r0 = x.x - __uint_as_float(h0 << 16);
  float r1 = x.y - __uint_as_float(h0 & 0xffff0000u);
  float r2 = x.z - __uint_as_float(h1 << 16);
  float r3 = x.w - __uint_as_float(h1 & 0xffff0000u);
  float r4 = y.x - __uint_as_float(h2 << 16);
  float r5 = y.y - __uint_as_float(h2 & 0xffff0000u);
  float r6 = y.z - __uint_as_float(h3 << 16);
  float r7 = y.w - __uint_as_float(h3 & 0xffff0000u);
  uint4 H = make_uint4(h0, h1, h2, h3);
  uint4 L = make_uint4(cvt_pk_bf16(r0, r1), cvt_pk_bf16(r2, r3),
                       cvt_pk_bf16(r4, r5), cvt_pk_bf16(r6, r7));
  hi = __builtin_bit_cast(bf16x8, H);
  lo = __builtin_bit_cast(bf16x8, L);
}
__device__ __forceinline__ bf16x8 hi8(const float4& x, const float4& y){
  uint4 H = make_uint4(cvt_pk_bf16(x.x,x.y), cvt_pk_bf16(x.z,x.w),
                       cvt_pk_bf16(y.x,y.y), cvt_pk_bf16(y.z,y.w));
  return __builtin_bit_cast(bf16x8, H);
}

// ---------------------------------------------------------------- K0a: small precomputes + c-side tanh maps
__global__ __launch_bounds__(256) void k0a_prep(
    const float* __restrict__ c, const float* __restrict__ c_mask,
    const float* __restrict__ c_param,
    const float* __restrict__ U, const float* __restrict__ W_c2p,
    const float* __restrict__ Wh_c, const float* __restrict__ bh_c,
    const float* __restrict__ b_c2p, const float* __restrict__ Wa_c,
    const float* __restrict__ Wa_p, const float* __restrict__ W_comb_c,
    const float* __restrict__ ba_c,
    float* __restrict__ uh, float* __restrict__ wccv,
    float* __restrict__ score_c, float2* __restrict__ pairP)
{
  int bid = blockIdx.x, t = threadIdx.x;
  if (bid < 4) {
    int h = bid;
    if (t < 128) {
      float s_uh = 0.f, s_wcc = 0.f;
      for (int d = 0; d < 128; ++d) {
        float cp = c_param[d];
        s_uh  += cp * U[(h*128 + d)*128 + t];
        s_wcc += cp * W_comb_c[(h*128 + d)*128 + t];
      }
      uh[h*128 + t]   = s_uh;
      wccv[h*128 + t] = s_wcc;
    }
  } else {
    int i = bid - 4;
    int b = i >> 4, h = (i >> 2) & 3, lc = i & 3;
    __shared__ float whc_l[128], wc2p_l[128], bhc_l[128], bc2p_l[128], wac1_l[128], wap2_l[128];
    if (t < 128) {
      float s1 = 0.f, s2 = 0.f;
      for (int d = 0; d < 128; ++d) {
        float cp = c_param[d];
        s1 += cp * Wh_c[(h*128 + d)*128 + t];
        s2 += cp * W_c2p[(h*128 + d)*128 + t];
      }
      whc_l[t] = s1; wc2p_l[t] = s2;
      bhc_l[t]  = bh_c[h*128 + t];
      bc2p_l[t] = b_c2p[h*128 + t];
      wac1_l[t] = Wa_c[h*256 + t];
      wap2_l[t] = Wa_p[h*256 + 128 + t];
    }
    __syncthreads();
    int l = lc*256 + t;
    float cl = c[b*1024 + l];
    float a1 = 0.f, a2 = 0.f;
    for (int e = 0; e < 128; ++e) {
      a1 += wac1_l[e] * tanh_fast(cl*whc_l[e]  + bhc_l[e]);
      a2 += wap2_l[e] * tanh_fast(cl*wc2p_l[e] + bc2p_l[e]);
    }
    int o = (b*4 + h)*1024 + l;
    score_c[o] = a1 + ba_c[h];                     // base: hcw + ba_c
    pairP[o] = make_float2(TWO_LOG2E * cl, c_mask[b*1024 + l] * a2); // (kappa, ctw)
  }
}

// ---------------------------------------------------------------- K0t: coalesced LDS-tile transposes -> hi/lo bf16
// 64 blocks: 0..31 p_param (1024x128), 32..47 W_p2c, 48..63 Wh_p (per-head 128x128).
__global__ __launch_bounds__(256) void k0t_transpose(
    const float* __restrict__ p_param, const float* __restrict__ W_p2c,
    const float* __restrict__ Wh_p,
    unsigned short* __restrict__ ppT_hi, unsigned short* __restrict__ ppT_lo,
    unsigned short* __restrict__ wp2cT_hi, unsigned short* __restrict__ wp2cT_lo,
    unsigned short* __restrict__ whpT_hi, unsigned short* __restrict__ whpT_lo)
{
  __shared__ float T[64*68];
  int bid = blockIdx.x, t = threadIdx.x;
  const float* src; unsigned short* dh; unsigned short* dl;
  int k0, e0, dpitch, drow0;
  if (bid < 32) {                 // pp tile: k-tile = bid>>1 (64 rows), e-tile = bid&1
    k0 = (bid >> 1)*64; e0 = (bid & 1)*64;
    src = p_param; dh = ppT_hi; dl = ppT_lo; dpitch = 1024; drow0 = e0;
  } else if (bid < 48) {
    int w = bid - 32; int h = w >> 2, ki = (w >> 1) & 1, ej = w & 1;
    k0 = ki*64; e0 = ej*64;
    src = W_p2c + h*16384; dh = wp2cT_hi; dl = wp2cT_lo; dpitch = 128;
    drow0 = h*128 + e0;
  } else {
    int w = bid - 48; int h = w >> 2, ki = (w >> 1) & 1, ej = w & 1;
    k0 = ki*64; e0 = ej*64;
    src = Wh_p + h*16384; dh = whpT_hi; dl = whpT_lo; dpitch = 128;
    drow0 = h*128 + e0;
  }
  {
    int r = t >> 2, cs = (t & 3)*4;
    const float* s = src + (k0 + r)*128 + e0 + cs;
    #pragma unroll
    for (int j = 0; j < 4; ++j) {
      float4 v = *(const float4*)(s + j*16);
      *(float4*)&T[r*68 + cs + j*16] = v;
    }
  }
  __syncthreads();
  {
    int e = t >> 2, ks = (t & 3)*16;
    unsigned short hs[16], ls[16];
    #pragma unroll
    for (int j = 0; j < 16; ++j) {
      float v = T[(ks + j)*68 + e];
      unsigned short hh = f2bf(v);
      hs[j] = hh; ls[j] = f2bf(v - bf2f(hh));
    }
    unsigned short* ph = dh + (drow0 + e)*dpitch + k0 + ks;
    unsigned short* pl = dl + (drow0 + e)*dpitch + k0 + ks;
    *(u16x8*)ph       = *(u16x8*)&hs[0];
    *(u16x8*)(ph + 8) = *(u16x8*)&hs[8];
    *(u16x8*)pl       = *(u16x8*)&ls[0];
    *(u16x8*)(pl + 8) = *(u16x8*)&ls[8];
  }
}

// ---------------------------------------------------------------- K1: pv = p @ p_param (split-bf16 MFMA) + g epilogue
__global__ __launch_bounds__(256) void k1_pv(
    const float* __restrict__ p,
    const unsigned short* __restrict__ ppT_hi, const unsigned short* __restrict__ ppT_lo,
    const float* __restrict__ uh,
    float* __restrict__ pv_f32, float* __restrict__ g_arr, float2* __restrict__ pairC)
{
  __shared__ __align__(16) short Bh[128*72];
  __shared__ __align__(16) short Bl[128*72];
  int t = threadIdx.x;
  int row0 = blockIdx.x * 64;
  int w = t >> 6, lane = t & 63;
  int l15 = lane & 15, l4 = lane >> 4;

  int bcol = t >> 1, bkh = (t & 1) * 32;
  const unsigned short* gBh = ppT_hi + bcol*1024 + bkh;
  const unsigned short* gBl = ppT_lo + bcol*1024 + bkh;
  short* sBh = &Bh[bcol*72 + bkh];
  short* sBl = &Bl[bcol*72 + bkh];

  const float* gA = p + (row0 + w*16 + l15)*1024 + l4*8;

  u16x8 rb[8];        // hi[0..3], lo[4..7]
  float4 ra[4];       // (ks,half): [2*ks+half]

  #pragma unroll
  for (int j = 0; j < 4; ++j) {
    rb[j]   = *(const u16x8*)(gBh + j*8);
    rb[4+j] = *(const u16x8*)(gBl + j*8);
  }
  #pragma unroll
  for (int j = 0; j < 4; ++j)
    ra[j] = *(const float4*)(gA + (j>>1)*32 + (j&1)*4);

  f32x4 acc[8];
  #pragma unroll
  for (int n = 0; n < 8; ++n) acc[n] = (f32x4){0.f,0.f,0.f,0.f};

  for (int kc = 0; kc < 16; ++kc) {
    __syncthreads();
    #pragma unroll
    for (int j = 0; j < 4; ++j) {
      *(u16x8*)(sBh + j*8) = rb[j];
      *(u16x8*)(sBl + j*8) = rb[4+j];
    }
    if (kc < 15) {
      #pragma unroll
      for (int j = 0; j < 4; ++j) {
        rb[j]   = *(const u16x8*)(gBh + (kc+1)*64 + j*8);
        rb[4+j] = *(const u16x8*)(gBl + (kc+1)*64 + j*8);
      }
    }
    float4 ran0, ran1, ran2, ran3;
    if (kc < 15) {
      const float* gAn = gA + (kc+1)*64;
      ran0 = *(const float4*)(gAn);
      ran1 = *(const float4*)(gAn + 4);
      ran2 = *(const float4*)(gAn + 32);
      ran3 = *(const float4*)(gAn + 36);
    }
    __syncthreads();
    #pragma unroll
    for (int ks = 0; ks < 2; ++ks) {
      bf16x8 ah, al;
      split8(ra[2*ks], ra[2*ks+1], ah, al);
      #pragma unroll
      for (int ct = 0; ct < 8; ++ct) {
        bf16x8 bh = *(const bf16x8*)&Bh[(ct*16 + l15)*72 + ks*32 + l4*8];
        bf16x8 bl = *(const bf16x8*)&Bl[(ct*16 + l15)*72 + ks*32 + l4*8];
        acc[ct] = __builtin_amdgcn_mfma_f32_16x16x32_bf16(ah, bh, acc[ct], 0, 0, 0);
        acc[ct] = __builtin_amdgcn_mfma_f32_16x16x32_bf16(ah, bl, acc[ct], 0, 0, 0);
        acc[ct] = __builtin_amdgcn_mfma_f32_16x16x32_bf16(al, bh, acc[ct], 0, 0, 0);
      }
    }
    if (kc < 15) { ra[0] = ran0; ra[1] = ran1; ra[2] = ran2; ra[3] = ran3; }
  }

  #pragma unroll
  for (int ct = 0; ct < 8; ++ct) {
    int col = ct*16 + l15;
    #pragma unroll
    for (int r = 0; r < 4; ++r) {
      int row = row0 + w*16 + l4*4 + r;
      pv_f32[row*128 + col] = acc[ct][r];
    }
  }

  // g epilogue: g[bh,m] = sum_d pv[m,d]*uh[h,d] from regs; also pairC.x
  #pragma unroll
  for (int h = 0; h < 4; ++h) {
    float s0 = 0.f, s1 = 0.f, s2 = 0.f, s3 = 0.f;
    #pragma unroll
    for (int ct = 0; ct < 8; ++ct) {
      float u = uh[h*128 + ct*16 + l15];
      s0 = fmaf(acc[ct][0], u, s0);
      s1 = fmaf(acc[ct][1], u, s1);
      s2 = fmaf(acc[ct][2], u, s2);
      s3 = fmaf(acc[ct][3], u, s3);
    }
    #pragma unroll
    for (int off = 1; off < 16; off <<= 1) {
      s0 += __shfl_xor(s0, off, 64);
      s1 += __shfl_xor(s1, off, 64);
      s2 += __shfl_xor(s2, off, 64);
      s3 += __shfl_xor(s3, off, 64);
    }
    if (l15 == 0) {
      int row = row0 + w*16 + l4*4;
      int bb = row >> 10, m = row & 1023;
      int idx = (bb*4 + h)*1024 + m;
      *(float4*)&g_arr[idx] = make_float4(s0, s1, s2, s3);
      pairC[idx+0].x = TWO_LOG2E * s0;
      pairC[idx+1].x = TWO_LOG2E * s1;
      pairC[idx+2].x = TWO_LOG2E * s2;
      pairC[idx+3].x = TWO_LOG2E * s3;
    }
  }
}

// ---------------------------------------------------------------- K2: weight-stationary per-(path,h) tanh transforms
// grid 1024: bid = ph*128 + mtile (128 rows). 128 % 8 == 0 -> all 8 ph blocks
// for one mtile land on the same XCD (pv tile XCD-local). W staged once in LDS.
__global__ __launch_bounds__(256) void k2_head(
    const float* __restrict__ pv_f32,
    const unsigned short* __restrict__ wp2cT_hi,
    const unsigned short* __restrict__ whpT_hi,
    const float* __restrict__ b_p2c, const float* __restrict__ bh_p,
    const float* __restrict__ Wa_c, const float* __restrict__ Wa_p,
    const float* __restrict__ p_mask, const float* __restrict__ ba_p,
    float2* __restrict__ pairC, float* __restrict__ score_p)
{
  __shared__ __align__(16) short Wlds[128*136];
  int t = threadIdx.x;
  int bid = blockIdx.x;
  int ph = bid >> 7, mtile = bid & 127;
  int path = ph >> 2, h = ph & 3;
  int w = t >> 6, lane = t & 63;
  int l15 = lane & 15, l4 = lane >> 4;

  const unsigned short* Wg = (path ? whpT_hi : wp2cT_hi) + h*16384;
  { // stage W[e][k] -> LDS (pitch 136): 64 shorts/thread, FULL coverage
    int e = t >> 1, k0 = (t & 1)*64;
    const u16x8* src = (const u16x8*)(Wg + e*128 + k0);
    u16x8* dst = (u16x8*)&Wlds[e*136 + k0];
    #pragma unroll
    for (int j = 0; j < 8; ++j) dst[j] = src[j];
  }

  // A fragments: 2 row-tiles x 4 kt (hi-bf16 only; K2 is score-level)
  int rowbase = mtile*128 + w*32;
  bf16x8 af[2][4];
  #pragma unroll
  for (int rt = 0; rt < 2; ++rt) {
    const float* ga = pv_f32 + (rowbase + rt*16 + l15)*128 + l4*8;
    #pragma unroll
    for (int kt = 0; kt < 4; ++kt) {
      float4 x = *(const float4*)(ga + kt*32);
      float4 y = *(const float4*)(ga + kt*32 + 4);
      af[rt][kt] = hi8(x, y);
    }
  }

  const float* bias_g = path ? bh_p : b_p2c;
  float biasv[8], wav[8];
  #pragma unroll
  for (int n = 0; n < 8; ++n) {
    int col = n*16 + l15;
    biasv[n] = bias_g[h*128 + col];
    wav[n]   = path ? Wa_p[h*256 + col] : Wa_c[h*256 + 128 + col];
  }

  __syncthreads();

  f32x4 acc[2][8];
  #pragma unroll
  for (int rt = 0; rt < 2; ++rt)
    #pragma unroll
    for (int n = 0; n < 8; ++n) acc[rt][n] = (f32x4){0.f,0.f,0.f,0.f};

  #pragma unroll
  for (int n = 0; n < 8; ++n) {
    #pragma unroll
    for (int kt = 0; kt < 4; ++kt) {
      bf16x8 bf = *(const bf16x8*)&Wlds[(n*16 + l15)*136 + kt*32 + l4*8];
      acc[0][n] = __builtin_amdgcn_mfma_f32_16x16x32_bf16(af[0][kt], bf, acc[0][n], 0, 0, 0);
      acc[1][n] = __builtin_amdgcn_mfma_f32_16x16x32_bf16(af[1][kt], bf, acc[1][n], 0, 0, 0);
    }
  }

  #pragma unroll
  for (int rt = 0; rt < 2; ++rt) {
    float pp0 = 0.f, pp1 = 0.f, pp2 = 0.f, pp3 = 0.f;
    #pragma unroll
    for (int n = 0; n < 8; ++n) {
      float bb = biasv[n], ww = wav[n];
      pp0 += ww * tanh_fast(acc[rt][n][0] + bb);
      pp1 += ww * tanh_fast(acc[rt][n][1] + bb);
      pp2 += ww * tanh_fast(acc[rt][n][2] + bb);
      pp3 += ww * tanh_fast(acc[rt][n][3] + bb);
    }
    #pragma unroll
    for (int off = 1; off < 16; off <<= 1) {
      pp0 += __shfl_xor(pp0, off, 64);
      pp1 += __shfl_xor(pp1, off, 64);
      pp2 += __shfl_xor(pp2, off, 64);
      pp3 += __shfl_xor(pp3, off, 64);
    }
    if (l15 == 0) {
      int grow = rowbase + rt*16 + l4*4;
      int bb = grow >> 10, m = grow & 1023;
      int idx = (bb*4 + h)*1024 + m;
      if (path) {
        float bap = ba_p[h];
        *(float4*)&score_p[idx] = make_float4(pp0+bap, pp1+bap, pp2+bap, pp3+bap);
      } else {
        float4 mk = *(const float4*)&p_mask[bb*1024 + m];
        pairC[idx+0].y = mk.x * pp0;
        pairC[idx+1].y = mk.y * pp1;
        pairC[idx+2].y = mk.z * pp2;
        pairC[idx+3].y = mk.w * pp3;
      }
    }
  }
}

// ---------------------------------------------------------------- K4: tanh outer-product reductions
// grid 2048 = side(2) x b(16) x h(4) x alpha-chunk(4) x j-chunk(4); 256 thr.
__global__ __launch_bounds__(256) void k4_scores(
    const float* __restrict__ c, const float* __restrict__ c_mask, const float* __restrict__ p_mask,
    const float* __restrict__ g_arr,
    const float2* __restrict__ pairC, const float2* __restrict__ pairP,
    float* __restrict__ score_c, float* __restrict__ score_p)
{
  __shared__ float red[4];
  int bid = blockIdx.x, t = threadIdx.x;
  int side = bid >> 10;
  int r = bid & 1023;
  int b = r >> 6, h = (r >> 4) & 3, ac = (r >> 2) & 3, jc = r & 3;
  int bh = b*4 + h;
  const float2* pair = (side ? pairP : pairC) + bh*1024 + jc*256;
  int ai = ac*256 + t;
  float alpha = side ? g_arr[bh*1024 + ai] : c[b*1024 + ai];
  float mask  = side ? p_mask[b*1024 + ai] : c_mask[b*1024 + ai];

  float partB = pair[t].y;
  #pragma unroll
  for (int off = 1; off < 64; off <<= 1) partB += __shfl_xor(partB, off, 64);
  if ((t & 63) == 0) red[t >> 6] = partB;
  __syncthreads();
  float sB = red[0] + red[1] + red[2] + red[3];

  float acc = 0.f;
  #pragma unroll 16
  for (int j = 0; j < 256; ++j) {
    float2 gb = pair[j];                      // block-uniform -> scalar loads
    float e = exp2_raw(alpha * gb.x);         // e^{2*alpha*g}, raw v_exp_f32
    acc = fmaf(gb.y, __builtin_amdgcn_rcpf(e + 1.0f), acc);
  }
  float part = mask * (sB - 2.0f*acc);
  atomicAdd((side ? score_p : score_c) + bh*1024 + ai, part);
}

// ---------------------------------------------------------------- K5: masked softmax + pools
__device__ __forceinline__ float blk_red_max(float v, float* red, int t){
  red[t] = v; __syncthreads();
  for (int s = 128; s; s >>= 1) { if (t < s) red[t] = fmaxf(red[t], red[t+s]); __syncthreads(); }
  float r = red[0]; __syncthreads();
  return r;
}
__device__ __forceinline__ float blk_red_sum(float v, float* red, int t){
  red[t] = v; __syncthreads();
  for (int s = 128; s; s >>= 1) { if (t < s) red[t] += red[t+s]; __syncthreads(); }
  float r = red[0]; __syncthreads();
  return r;
}

__global__ __launch_bounds__(256) void k5_soft(
    const float* __restrict__ c, const float* __restrict__ c_mask, const float* __restrict__ p_mask,
    const float* __restrict__ score_c, const float* __restrict__ score_p,
    const float* __restrict__ pv_f32,
    float* __restrict__ s_c, float* __restrict__ pf_pool)
{
  __shared__ float sv[1024];
  __shared__ float red[256];
  int bid = blockIdx.x, t = threadIdx.x;
  bool sideP = bid >= 64;
  int i = bid & 63;
  int b = i >> 2, h = i & 3, bh = b*4 + h;
  const float* sc = (sideP ? score_p : score_c) + bh*1024;
  const float* mk = (sideP ? p_mask : c_mask) + b*1024;

  float v[4];
  float mx = -1e30f;
  #pragma unroll
  for (int j = 0; j < 4; ++j) { v[j] = sc[t + j*256]; mx = fmaxf(mx, v[j]); }
  mx = blk_red_max(mx, red, t);
  float sum = 0.f;
  #pragma unroll
  for (int j = 0; j < 4; ++j) {
    float e = exp2_raw((v[j] - mx) * 1.4426950408889634f) * mk[t + j*256];
    sv[t + j*256] = e;
    sum += e;
  }
  sum = blk_red_sum(sum, red, t);
  float rinv = __fdividef(1.0f, sum + 1e-6f);

  if (!sideP) {
    float a = 0.f;
    #pragma unroll
    for (int j = 0; j < 4; ++j) a += sv[t + j*256] * rinv * c[b*1024 + t + j*256];
    a = blk_red_sum(a, red, t);
    if (t == 0) s_c[bh] = a;
  } else {
    #pragma unroll
    for (int j = 0; j < 4; ++j) sv[t + j*256] *= rinv;
    __syncthreads();
    int e = t & 127, half = t >> 7;
    float acc = 0.f;
    const float* base = pv_f32 + (b*1024 + half*512)*128 + e;
    #pragma unroll 4
    for (int m = 0; m < 512; ++m) acc += sv[half*512 + m] * base[m*128];
    red[t] = acc; __syncthreads();
    if (t < 128) pf_pool[bh*128 + t] = red[t] + red[t + 128];
  }
}

// ---------------------------------------------------------------- K6: finals + outer product
__global__ __launch_bounds__(256) void k6_final(
    const float* __restrict__ s_c, const float* __restrict__ wccv,
    const float* __restrict__ b_comb_c, const float* __restrict__ pf_pool,
    const float* __restrict__ W_comb_p, const float* __restrict__ b_comb_p,
    float* __restrict__ out)
{
  __shared__ float pfr[512];
  __shared__ float cfl[128], pfl[128];
  int b = blockIdx.x, t = threadIdx.x;
  pfr[t]       = pf_pool[b*512 + t];
  pfr[t + 256] = pf_pool[b*512 + t + 256];
  __syncthreads();
  if (t < 128) {
    float cf = b_comb_c[t];
    #pragma unroll
    for (int h = 0; h < 4; ++h) cf += s_c[b*4 + h] * wccv[h*128 + t];
    float pf = b_comb_p[t];
    #pragma unroll 8
    for (int i = 0; i < 512; ++i) pf += pfr[i] * W_comb_p[i*128 + t];
    cfl[t] = cf; pfl[t] = pf;
  }
  __syncthreads();
  #pragma unroll
  for (int k = 0; k < 64; ++k) {
    int idx = k*256 + t;
    out[b*16384 + idx] = cfl[idx >> 7] * pfl[idx & 127];
  }
}

// ---------------------------------------------------------------- launcher
extern "C" void kernel_launch(void* const* d_in, const int* in_sizes, int n_in,
                              void* d_out, int out_size, void* d_ws, size_t ws_size,
                              hipStream_t stream)
{
  const float* c        = (const float*)d_in[0];
  const float* c_mask   = (const float*)d_in[1];
  const float* p        = (const float*)d_in[2];
  const float* p_mask   = (const float*)d_in[3];
  const float* c_param  = (const float*)d_in[4];
  const float* p_param  = (const float*)d_in[5];
  const float* U        = (const float*)d_in[6];
  const float* W_p2c    = (const float*)d_in[7];
  const float* b_p2c    = (const float*)d_in[8];
  const float* W_c2p    = (const float*)d_in[9];
  const float* b_c2p    = (const float*)d_in[10];
  const float* Wh_c     = (const float*)d_in[11];
  const float* bh_c     = (const float*)d_in[12];
  const float* Wh_p     = (const float*)d_in[13];
  const float* bh_p     = (const float*)d_in[14];
  const float* Wa_c     = (const float*)d_in[15];
  const float* ba_c     = (const float*)d_in[16];
  const float* Wa_p     = (const float*)d_in[17];
  const float* ba_p     = (const float*)d_in[18];
  const float* W_comb_c = (const float*)d_in[19];
  const float* b_comb_c = (const float*)d_in[20];
  const float* W_comb_p = (const float*)d_in[21];
  const float* b_comb_p = (const float*)d_in[22];
  float* out = (float*)d_out;

  char* ws = (char*)d_ws;
  float*          pv_f32   = (float*)         (ws + 0);
  unsigned short* ppT_hi   = (unsigned short*)(ws + 8388608);
  unsigned short* ppT_lo   = (unsigned short*)(ws + 8650752);
  unsigned short* wp2cT_hi = (unsigned short*)(ws + 8912896);
  unsigned short* wp2cT_lo = (unsigned short*)(ws + 9043968);
  unsigned short* whpT_hi  = (unsigned short*)(ws + 9175040);
  unsigned short* whpT_lo  = (unsigned short*)(ws + 9306112);
  float*          uh       = (float*)         (ws + 9437184);
  float*          wccv     = (float*)         (ws + 9439232);
  float*          g_arr    = (float*)         (ws + 9441280);
  float2*         pairC    = (float2*)        (ws + 9703424);
  float2*         pairP    = (float2*)        (ws + 10227712);
  float*          score_c  = (float*)         (ws + 10752000);
  float*          score_p  = (float*)         (ws + 11014144);
  float*          s_c      = (float*)         (ws + 11276288);
  float*          pf_pool  = (float*)         (ws + 11276544);

  k0a_prep<<<dim3(260), dim3(256), 0, stream>>>(
      c, c_mask, c_param, U, W_c2p, Wh_c, bh_c, b_c2p, Wa_c, Wa_p,
      W_comb_c, ba_c, uh, wccv, score_c, pairP);

  k0t_transpose<<<dim3(64), dim3(256), 0, stream>>>(
      p_param, W_p2c, Wh_p,
      ppT_hi, ppT_lo, wp2cT_hi, wp2cT_lo, whpT_hi, whpT_lo);

  k1_pv<<<dim3(256), dim3(256), 0, stream>>>(p, ppT_hi, ppT_lo, uh, pv_f32, g_arr, pairC);

  k2_head<<<dim3(1024), dim3(256), 0, stream>>>(
      pv_f32, wp2cT_hi, whpT_hi,
      b_p2c, bh_p, Wa_c, Wa_p, p_mask, ba_p, pairC, score_p);

  k4_scores<<<dim3(2048), dim3(256), 0, stream>>>(
      c, c_mask, p_mask, g_arr, pairC, pairP, score_c, score_p);

  k5_soft<<<dim3(128), dim3(256), 0, stream>>>(
      c, c_mask, p_mask, score_c, score_p, pv_f32, s_c, pf_pool);

  k6_final<<<dim3(16), dim3(256), 0, stream>>>(
      s_c, wccv, b_comb_c, pf_pool, W_comb_p, b_comb_p, out);
}